// Round 19
// baseline (98.333 us; speedup 1.0000x reference)
//
#include <hip/hip_runtime.h>
#include <hip/hip_bf16.h>
#include <math.h>

#define IN_DIM     128
#define OUT_DIM    64
#define BSHIFT     8                  // 256 nodes per bucket
#define BSZ        256
#define NBUCK_MAX  512                // covers N <= 131072
#define EPB        4096               // edges per block in bucket pass
#define EPT        16                 // edges per thread (EPB/256)
#define CAPMAX     5120               // LDS staging limit (20 KB)

typedef __attribute__((ext_vector_type(4))) float  f32x4;
typedef __attribute__((ext_vector_type(2))) float  f32x2;
typedef __attribute__((ext_vector_type(8))) short  bf16x8;

// bf16 helpers
__device__ __forceinline__ unsigned int pk_bf2(float lo, float hi) {
    __hip_bfloat162 h = __float22bfloat162_rn(make_float2(lo, hi));
    unsigned int u;
    __builtin_memcpy(&u, &h, 4);
    return u;
}
__device__ __forceinline__ float bf_lo(unsigned int v) { return __uint_as_float(v << 16); }
__device__ __forceinline__ float bf_hi(unsigned int v) { return __uint_as_float(v & 0xFFFF0000u); }
// unpack bf16 pair -> f32x2 {lo, hi}
__device__ __forceinline__ f32x2 unpk2(unsigned int v) {
    f32x2 r;
    r.x = bf_lo(v);
    r.y = bf_hi(v);
    return r;
}

// ---------------------------------------------------------------------------
// Bucket scatter (single global pass, register-staged) + wtab pack.
//   blocks [0, nchunk): scatter packed (r<<8 | c&255) into tmp[b*CAP ...]
//   block nchunk:       pack W into MFMA B-frag order (bf16, 16 KB)
// bcursor must be pre-zeroed (hipMemsetAsync).
// ---------------------------------------------------------------------------
__global__ __launch_bounds__(256) void bucket_kernel(
        const int* __restrict__ eidx, const float* __restrict__ W,
        unsigned int* __restrict__ wtab, int* __restrict__ bcursor,
        int* __restrict__ tmp, int E, int nbuck, int CAP, int nchunk) {
    __shared__ int hcnt[NBUCK_MAX];
    __shared__ int hbase[NBUCK_MAX];
    const int tid = threadIdx.x;

    if (blockIdx.x == nchunk) {
        // ---------------- wtab pack (one block) ----------------
#pragma unroll
        for (int ii = 0; ii < 4; ++ii) {
            int fl = ii * 256 + tid, f = fl >> 6, lane = fl & 63;
            int ct = f >> 2, kt = f & 3;
            int n  = ct * 16 + (lane & 15);
            int kb = kt * 32 + (lane >> 4) * 8;
            unsigned int q[4];
#pragma unroll
            for (int e = 0; e < 4; ++e)
                q[e] = pk_bf2(W[(kb + 2 * e) * OUT_DIM + n],
                              W[(kb + 2 * e + 1) * OUT_DIM + n]);
            *reinterpret_cast<uint4*>(&wtab[fl * 4]) = *reinterpret_cast<uint4*>(q);
        }
        return;
    }

    // ---------------- bucket scatter ----------------
    for (int i = tid; i < nbuck; i += 256) hcnt[i] = 0;
    __syncthreads();

    const int base = blockIdx.x * EPB;
    const int* col = eidx + E;

    int er[EPT], ec[EPT];
#pragma unroll
    for (int j = 0; j < EPT; ++j) {
        int e = base + j * 256 + tid;
        if (e < E) {
            er[j] = eidx[e];
            ec[j] = col[e];
            atomicAdd(&hcnt[ec[j] >> BSHIFT], 1);
        } else {
            ec[j] = -1;
        }
    }
    __syncthreads();

    for (int i = tid; i < nbuck; i += 256) {
        int n = hcnt[i];
        hbase[i] = n ? (i * CAP + atomicAdd(&bcursor[i], n)) : 0;
        hcnt[i] = 0;                        // reuse as local cursor
    }
    __syncthreads();

#pragma unroll
    for (int j = 0; j < EPT; ++j) {
        if (ec[j] >= 0) {
            int bb = ec[j] >> BSHIFT;
            int ofs = atomicAdd(&hcnt[bb], 1);
            int pos = hbase[bb] + ofs;
            if (pos < (bb + 1) * CAP)       // overflow guard (8-sigma margin)
                tmp[pos] = (er[j] << BSHIFT) | (ec[j] & (BSZ - 1));
        }
    }
}

// ---------------------------------------------------------------------------
// fusedB (spatial partition, block-uniform branch):
//   blocks [0, nbuck):          sortloc = count + scan + in-place CSR
//                               placement; emits rowptr + dis + bend
//   blocks [nbuck, +nblk_lin):  MFMA linear, hsb = bf16(x @ W)  [UNscaled]
// ---------------------------------------------------------------------------
__global__ __launch_bounds__(256) void fusedB_kernel(
        int* __restrict__ tmp, const int* __restrict__ bcursor,
        int* __restrict__ rowptr, float* __restrict__ dis,
        int* __restrict__ bend,
        const float* __restrict__ x, const unsigned int* __restrict__ wtab,
        unsigned int* __restrict__ hsb, int N, int CAP, int nbuck) {
    __shared__ int sedge[CAPMAX];          // 20 KB
    __shared__ int scnt[BSZ];
    __shared__ int spref[BSZ];
    __shared__ int sscur[BSZ];

    const int tid = threadIdx.x;

    if (blockIdx.x < nbuck) {
        // ---------------- sortloc ----------------
        const int b    = blockIdx.x;
        const int base = b * CAP;
        const int cnt  = min(bcursor[b], CAP);

        scnt[tid] = 0;
        sscur[tid] = 0;
        __syncthreads();

        for (int i = tid; i < cnt; i += 256) {
            int p = tmp[base + i];
            sedge[i] = p;
            atomicAdd(&scnt[p & (BSZ - 1)], 1);
        }
        __syncthreads();

        int v = scnt[tid];
        spref[tid] = v;
        __syncthreads();
        for (int off = 1; off < 256; off <<= 1) {
            int t2 = (tid >= off) ? spref[tid - off] : 0;
            __syncthreads();
            spref[tid] += t2;
            __syncthreads();
        }
        int excl = spref[tid] - v;

        const int node = (b << BSHIFT) + tid;
        if (node < N) {
            rowptr[node] = base + excl;
            dis[node] = (v > 0) ? rsqrtf((float)v) : 0.f;
        }
        spref[tid] = excl;
        if (tid == 0) bend[b] = base + cnt;
        __syncthreads();

        for (int i = tid; i < cnt; i += 256) {
            int p = sedge[i];
            int c = p & (BSZ - 1);
            int pos = base + spref[c] + atomicAdd(&sscur[c], 1);
            tmp[pos] = p >> BSHIFT;
        }
    } else {
        // ---------------- MFMA linear (unscaled) ----------------
        const int lane6 = tid & 63;
        const int wv    = tid >> 6;
        const int tile    = (blockIdx.x - nbuck) * 4 + wv;
        const int rowbase = tile * 16;
        if (rowbase >= N) return;

        bf16x8 b[16];
#pragma unroll
        for (int f = 0; f < 16; ++f)
            b[f] = *reinterpret_cast<const bf16x8*>(&wtab[(f * 64 + lane6) * 4]);

        const int arow  = rowbase + (lane6 & 15);
        const int kbase = (lane6 >> 4) * 8;
        bf16x8 a[4];
#pragma unroll
        for (int kt = 0; kt < 4; ++kt) {
            const float4* p = reinterpret_cast<const float4*>(
                &x[(size_t)arow * IN_DIM + kt * 32 + kbase]);
            float4 f0 = p[0], f1 = p[1];
            unsigned int q[4] = { pk_bf2(f0.x, f0.y), pk_bf2(f0.z, f0.w),
                                  pk_bf2(f1.x, f1.y), pk_bf2(f1.z, f1.w) };
            a[kt] = *reinterpret_cast<bf16x8*>(q);
        }

        f32x4 acc[4] = {{0,0,0,0},{0,0,0,0},{0,0,0,0},{0,0,0,0}};
#pragma unroll
        for (int ct = 0; ct < 4; ++ct)
#pragma unroll
            for (int kt = 0; kt < 4; ++kt)
                acc[ct] = __builtin_amdgcn_mfma_f32_16x16x32_bf16(
                    a[kt], b[ct * 4 + kt], acc[ct], 0, 0, 0);

        const int rbase = rowbase + (lane6 >> 4) * 4;
#pragma unroll
        for (int ct = 0; ct < 4; ++ct) {
#pragma unroll
            for (int r = 0; r < 4; ++r) {
                float v  = acc[ct][r];
                float vn = __shfl_down(v, 1, 64);
                if ((lane6 & 1) == 0) {
                    int cpair = ct * 8 + ((lane6 & 15) >> 1);
                    hsb[(size_t)(rbase + r) * (OUT_DIM / 2) + cpair] = pk_bf2(v, vn);
                }
            }
        }
    }
}

// ---------------------------------------------------------------------------
// Aggregate + bias + PReLU, eighth-wave layout: each 8-lane eighth processes
// its own edge (8 lanes x uint4 = 128B row). 8 edges per instruction slot,
// 2-deep unroll. Inner math uses f32x2 packed FMA (v_pk_fma_f32): per uint4,
// 8 unpack + 4 pk_fma instead of 8 unpack + 8 fma.
// ---------------------------------------------------------------------------
__global__ __launch_bounds__(256) void agg_kernel(
        const int* __restrict__ rowptr, const int* __restrict__ src,
        const int* __restrict__ bend,
        const uint4* __restrict__ hsb4, const float* __restrict__ dis,
        const float* __restrict__ b, const float* __restrict__ prelu_a,
        float* __restrict__ out, int N) {
    const int lane = threadIdx.x & 63;
    const int e8   = lane >> 3;        // eighth 0..7
    const int s    = lane & 7;         // sublane within eighth
    const int node = (blockIdx.x * blockDim.x + threadIdx.x) >> 6;
    if (node >= N) return;

    const int beg = rowptr[node];
    const int nb1 = node + 1;
    const int end = ((nb1 & (BSZ - 1)) != 0 && nb1 < N) ? rowptr[nb1]
                                                        : bend[node >> BSHIFT];

    f32x2 A0 = {0.f, 0.f}, A1 = {0.f, 0.f}, A2 = {0.f, 0.f}, A3 = {0.f, 0.f};
    int p = beg + e8;

    // 2 slots x 8 eighths = 16 edges per iteration, 2 gathers in flight/lane
    for (; p + 8 < end; p += 16) {
        int r0 = src[p], r1 = src[p + 8];
        f32x2 s0 = {dis[r0], dis[r0]};
        f32x2 s1 = {dis[r1], dis[r1]};
        uint4 v0 = hsb4[r0 * 8 + s];
        uint4 v1 = hsb4[r1 * 8 + s];
        A0 = __builtin_elementwise_fma(unpk2(v0.x), s0, A0);
        A1 = __builtin_elementwise_fma(unpk2(v0.y), s0, A1);
        A2 = __builtin_elementwise_fma(unpk2(v0.z), s0, A2);
        A3 = __builtin_elementwise_fma(unpk2(v0.w), s0, A3);
        A0 = __builtin_elementwise_fma(unpk2(v1.x), s1, A0);
        A1 = __builtin_elementwise_fma(unpk2(v1.y), s1, A1);
        A2 = __builtin_elementwise_fma(unpk2(v1.z), s1, A2);
        A3 = __builtin_elementwise_fma(unpk2(v1.w), s1, A3);
    }
    // singles (one edge per eighth)
    for (; p < end; p += 8) {
        int r = src[p];
        f32x2 sc = {dis[r], dis[r]};
        uint4 v = hsb4[r * 8 + s];
        A0 = __builtin_elementwise_fma(unpk2(v.x), sc, A0);
        A1 = __builtin_elementwise_fma(unpk2(v.y), sc, A1);
        A2 = __builtin_elementwise_fma(unpk2(v.z), sc, A2);
        A3 = __builtin_elementwise_fma(unpk2(v.w), sc, A3);
    }

    // combine the 8 eighths (lane bits 3,4,5)
    float acc[8] = { A0.x, A0.y, A1.x, A1.y, A2.x, A2.y, A3.x, A3.y };
#pragma unroll
    for (int k = 0; k < 8; ++k) {
        acc[k] += __shfl_xor(acc[k], 8, 64);
        acc[k] += __shfl_xor(acc[k], 16, 64);
        acc[k] += __shfl_xor(acc[k], 32, 64);
    }

    if (e8 == 0) {
        const float dn = dis[node];
        const float pa = prelu_a[0];
        const int c0 = s * 8;
        float o[8];
#pragma unroll
        for (int k = 0; k < 8; ++k) {
            float v = acc[k] * dn + b[c0 + k];
            o[k] = (v >= 0.f) ? v : pa * v;
        }
        float4* po = reinterpret_cast<float4*>(&out[(size_t)node * OUT_DIM + c0]);
        po[0] = make_float4(o[0], o[1], o[2], o[3]);
        po[1] = make_float4(o[4], o[5], o[6], o[7]);
    }
}

extern "C" void kernel_launch(void* const* d_in, const int* in_sizes, int n_in,
                              void* d_out, int out_size, void* d_ws, size_t ws_size,
                              hipStream_t stream) {
    const float* x    = (const float*)d_in[0];
    const int*   eidx = (const int*)d_in[1];
    const float* W    = (const float*)d_in[2];
    const float* b    = (const float*)d_in[3];
    const float* pa   = (const float*)d_in[4];
    float* out = (float*)d_out;

    const int N = in_sizes[0] / IN_DIM;        // 100000
    const int E = in_sizes[1] / 2;             // 1600000
    const int nbuck  = (N + BSZ - 1) >> BSHIFT;   // 391
    const int nchunk = (E + EPB - 1) / EPB;       // 391
    const int ntiles = (N + 15) / 16;             // 6250
    const int nblk_lin = (ntiles + 3) / 4;        // 1563

    // fixed bucket capacity: mean + 8 sigma, rounded to 256, capped by LDS
    int avg = E / nbuck;
    int CAP = ((avg + 8 * (int)sqrt((double)avg) + 255) / 256) * 256;
    if (CAP > CAPMAX) CAP = CAPMAX;

    // workspace layout (4-byte elements):
    unsigned int* hsb = (unsigned int*)d_ws;                  // N*32 (bf16x2)
    int*   bcursor = (int*)(hsb + (size_t)N * (OUT_DIM / 2)); // NBUCK_MAX
    int*   bend    = bcursor + NBUCK_MAX;                     // NBUCK_MAX
    int*   rowptr  = bend + NBUCK_MAX;                        // N
    float* dis     = (float*)(rowptr + N);                    // N
    int*   tmp     = (int*)(dis + N);                         // nbuck*CAP
    unsigned int* wtab = (unsigned int*)(tmp + (size_t)nbuck * CAP); // 4096

    // 1) zero bcursor (graph-capturable memset node)
    hipMemsetAsync(bcursor, 0, NBUCK_MAX * sizeof(int), stream);

    // 2) bucket scatter (single global pass) + wtab pack (extra block)
    bucket_kernel<<<nchunk + 1, 256, 0, stream>>>(
        eidx, W, wtab, bcursor, tmp, E, nbuck, CAP, nchunk);

    // 3) fused: sortloc (count+scan+place, emits rowptr/dis/bend) || MFMA linear
    fusedB_kernel<<<nbuck + nblk_lin, 256, 0, stream>>>(
        tmp, bcursor, rowptr, dis, bend, x, wtab, hsb, N, CAP, nbuck);

    // 4) aggregate (eighth-wave uint4, packed FMA) + bias + PReLU
    agg_kernel<<<(N * 64 + 255) / 256, 256, 0, stream>>>(
        rowptr, tmp, bend, (const uint4*)hsb, dis, b, pa, out, N);
}